// Round 1
// baseline (1469.735 us; speedup 1.0000x reference)
//
#include <hip/hip_runtime.h>

// Problem constants (from reference)
#define NUu 200000
#define NIi 100000
#define EE  600000
// D = H = 128

typedef short short8 __attribute__((ext_vector_type(8)));
typedef float floatx4 __attribute__((ext_vector_type(4)));

// float -> bf16 bits, round-to-nearest-even
__device__ __forceinline__ unsigned short f2bf(float f) {
  union { float f; unsigned int u; } v; v.f = f;
  unsigned int r = v.u + 0x7FFFu + ((v.u >> 16) & 1u);
  return (unsigned short)(r >> 16);
}

__device__ __forceinline__ void atomAddF(float* p, float v) {
#if defined(__gfx950__) || defined(__gfx942__) || defined(__gfx90a__)
  unsafeAtomicAdd(p, v);   // HW global_atomic_add_f32
#else
  atomicAdd(p, v);
#endif
}

// ---------------------------------------------------------------------------
// K0a: fused weights  W1 = Wl @ W2nd,  W2 = Wr @ W2nd  -> bf16, packed in the
// MFMA B-fragment layout:  elem index = ((n_tile*8 + k_step)*64 + quad*16 + n_lo)*8 + j
// where k_global = k_step*32 + quad*8 + j, n = n_tile*16 + n_lo.
// grid: (128 d-rows, 4 matrices), block: 128 (thread = h)
// ---------------------------------------------------------------------------
__global__ __launch_bounds__(128) void fuse_weights(
    const float* __restrict__ Wl_iu, const float* __restrict__ Wr_iu,
    const float* __restrict__ Wl_ui, const float* __restrict__ Wr_ui,
    const float* __restrict__ W_user, const float* __restrict__ W_item,
    unsigned short* __restrict__ Wp_user, unsigned short* __restrict__ Wp_item)
{
  int d = blockIdx.x;        // 0..127 (row of first factor)
  int m = blockIdx.y;        // which matrix
  int h = threadIdx.x;       // 0..127 (output col)
  const float* A; const float* W; unsigned short* dst; int koff;
  switch (m) {
    case 0:  A = Wl_iu; W = W_user; dst = Wp_user; koff = 0;   break;
    case 1:  A = Wr_iu; W = W_user; dst = Wp_user; koff = 128; break;
    case 2:  A = Wl_ui; W = W_item; dst = Wp_item; koff = 0;   break;
    default: A = Wr_ui; W = W_item; dst = Wp_item; koff = 128; break;
  }
  float acc = 0.f;
  for (int k = 0; k < 128; ++k) acc += A[d * 128 + k] * W[k * 128 + h];
  int kg = koff + d;
  int ks = kg >> 5, quad = (kg >> 3) & 3, j = kg & 7;
  int nt = h >> 4, nlo = h & 15;
  int idx = ((nt * 8 + ks) * 64 + quad * 16 + nlo) * 8 + j;
  dst[idx] = f2bf(acc);
}

// K0b: fused bias = bl @ W2nd + b2nd   (fp32). grid 2, block 128.
__global__ __launch_bounds__(128) void fuse_bias(
    const float* __restrict__ bl_iu, const float* __restrict__ b_user, const float* __restrict__ Wu,
    const float* __restrict__ bl_ui, const float* __restrict__ b_item, const float* __restrict__ Wi,
    float* __restrict__ bias_user, float* __restrict__ bias_item)
{
  int h = threadIdx.x;
  const float* bl = blockIdx.x ? bl_ui : bl_iu;
  const float* b2 = blockIdx.x ? b_item : b_user;
  const float* W  = blockIdx.x ? Wi : Wu;
  float* o        = blockIdx.x ? bias_item : bias_user;
  float acc = b2[h];
  for (int k = 0; k < 128; ++k) acc += bl[k] * W[k * 128 + h];
  o[h] = acc;
}

// ---------------------------------------------------------------------------
// K2: scatter-add. One 64-lane wave per edge; each lane handles a float2 of
// the 128-wide feature row. fp32 HW atomics into agg[dst], int atomic count.
// ---------------------------------------------------------------------------
__global__ __launch_bounds__(256) void scatter(
    const float* __restrict__ xsrc, const int* __restrict__ esrc,
    const int* __restrict__ edst, float* __restrict__ agg, int* __restrict__ cnt)
{
  int gid = blockIdx.x * 256 + threadIdx.x;
  int e = gid >> 6;
  if (e >= EE) return;
  int lane = gid & 63;
  int s = esrc[e];
  int d = edst[e];
  float2 v = ((const float2*)(xsrc + (size_t)s * 128))[lane];
  float* a = agg + (size_t)d * 128 + lane * 2;
  atomAddF(a, v.x);
  atomAddF(a + 1, v.y);
  if (lane == 0) atomicAdd(cnt + d, 1);
}

// ---------------------------------------------------------------------------
// K3: fused node kernel: out = relu( (agg/max(cnt,1)) @ W1 + x @ W2 + bias )
// One block = 64 nodes x 128 outputs. A (64x256, mean-scaled, bf16) staged in
// LDS in the MFMA A-frag layout; B-frags (pre-packed) read from global (L2-hot).
// mfma_f32_16x16x32_bf16:  A[m=lane&15][k=(lane>>4)*8+j],
//                          B[k=(lane>>4)*8+j][n=lane&15],
//                          C/D: col=lane&15, row=(lane>>4)*4+reg   (m89/m91)
// ---------------------------------------------------------------------------
__global__ __launch_bounds__(256, 2) void fused_gemm(
    const float* __restrict__ xbase, const float* __restrict__ aggbase,
    const int* __restrict__ cnt, const unsigned short* __restrict__ Wp,
    const float* __restrict__ bias, float* __restrict__ outbase, int nvalid)
{
  __shared__ uint4 ldsA4[2048];                    // 32 KB packed A
  int t = threadIdx.x;
  int node0 = blockIdx.x * 64;

  // ---- stage A: 64 nodes x 256 k (k<128: agg*inv_deg, k>=128: x), bf16 ----
  #pragma unroll
  for (int i = 0; i < 8; ++i) {
    int oid = t + i * 256;                         // 0..2047 octet id
    int m = oid >> 5;                              // node within block (0..63)
    int oct = oid & 31;                            // 8-float chunk (k0 = oct*8)
    int k0 = oct * 8;
    int node = node0 + m;
    float vals[8];
    if (node < nvalid) {
      const float* src; float scale;
      if (k0 < 128) {
        src = aggbase + (size_t)node * 128 + k0;
        int c = cnt[node];
        scale = 1.0f / (float)(c > 0 ? c : 1);
      } else {
        src = xbase + (size_t)node * 128 + (k0 - 128);
        scale = 1.0f;
      }
      float4 lo = ((const float4*)src)[0];
      float4 hi = ((const float4*)src)[1];
      vals[0] = lo.x * scale; vals[1] = lo.y * scale;
      vals[2] = lo.z * scale; vals[3] = lo.w * scale;
      vals[4] = hi.x * scale; vals[5] = hi.y * scale;
      vals[6] = hi.z * scale; vals[7] = hi.w * scale;
    } else {
      #pragma unroll
      for (int j2 = 0; j2 < 8; ++j2) vals[j2] = 0.f;
    }
    uint4 p;
    p.x = (unsigned)f2bf(vals[0]) | ((unsigned)f2bf(vals[1]) << 16);
    p.y = (unsigned)f2bf(vals[2]) | ((unsigned)f2bf(vals[3]) << 16);
    p.z = (unsigned)f2bf(vals[4]) | ((unsigned)f2bf(vals[5]) << 16);
    p.w = (unsigned)f2bf(vals[6]) | ((unsigned)f2bf(vals[7]) << 16);
    int ks = oct >> 2, quad = oct & 3;
    int mt = m >> 4, mlo = m & 15;
    ldsA4[(mt * 8 + ks) * 64 + quad * 16 + mlo] = p;
  }
  __syncthreads();

  // ---- MFMA: wave = m-tile (16 nodes), 8 n-tiles, K = 256 in 8 steps ----
  int wave = t >> 6, lane = t & 63;
  floatx4 acc[8];
  #pragma unroll
  for (int i = 0; i < 8; ++i) acc[i] = (floatx4){0.f, 0.f, 0.f, 0.f};
  const short8* A = (const short8*)ldsA4;
  const short8* B = (const short8*)Wp;
  #pragma unroll
  for (int ks = 0; ks < 8; ++ks) {
    short8 af = A[(wave * 8 + ks) * 64 + lane];
    #pragma unroll
    for (int nt = 0; nt < 8; ++nt) {
      short8 bf = B[(nt * 8 + ks) * 64 + lane];
      acc[nt] = __builtin_amdgcn_mfma_f32_16x16x32_bf16(af, bf, acc[nt], 0, 0, 0);
    }
  }

  // ---- epilogue: bias + relu, C/D mapping col=lane&15 row=quad*4+reg ----
  int col = lane & 15, qrow = (lane >> 4) * 4;
  #pragma unroll
  for (int nt = 0; nt < 8; ++nt) {
    int n = nt * 16 + col;
    float bv = bias[n];
    #pragma unroll
    for (int r = 0; r < 4; ++r) {
      int node = node0 + wave * 16 + qrow + r;
      if (node < nvalid) {
        float v = acc[nt][r] + bv;
        outbase[(size_t)node * 128 + n] = v > 0.f ? v : 0.f;
      }
    }
  }
}

// ---------------------------------------------------------------------------
// Workspace layout (bytes):
//   agg_user  [NU*128 f32]  @ 0            = 102,400,000
//   agg_item  [NI*128 f32]  @ 102,400,000  =  51,200,000
//   cnt_user  [NU i32]      @ 153,600,000  =     800,000
//   cnt_item  [NI i32]      @ 154,400,000  =     400,000
//   Wp_user   [256x128 bf16]@ 154,800,000  =      65,536
//   Wp_item   [256x128 bf16]@ 154,865,536  =      65,536
//   bias_user [128 f32]     @ 154,931,072  =         512
//   bias_item [128 f32]     @ 154,931,584  =         512
// total ~154.93 MB
// ---------------------------------------------------------------------------
extern "C" void kernel_launch(void* const* d_in, const int* in_sizes, int n_in,
                              void* d_out, int out_size, void* d_ws, size_t ws_size,
                              hipStream_t stream)
{
  const float* x_user = (const float*)d_in[0];
  const float* x_item = (const float*)d_in[1];
  const int* esrc_ui  = (const int*)d_in[2];
  const int* edst_ui  = (const int*)d_in[3];
  const int* esrc_iu  = (const int*)d_in[4];
  const int* edst_iu  = (const int*)d_in[5];
  const float* Wl_ui  = (const float*)d_in[6];
  const float* bl_ui  = (const float*)d_in[7];
  const float* Wr_ui  = (const float*)d_in[8];
  const float* Wl_iu  = (const float*)d_in[9];
  const float* bl_iu  = (const float*)d_in[10];
  const float* Wr_iu  = (const float*)d_in[11];
  const float* W_user = (const float*)d_in[12];
  const float* b_user = (const float*)d_in[13];
  const float* W_item = (const float*)d_in[14];
  const float* b_item = (const float*)d_in[15];
  float* out = (float*)d_out;

  char* ws = (char*)d_ws;
  float* agg_user = (float*)(ws);
  float* agg_item = (float*)(ws + 102400000);
  int*   cnt_user = (int*)(ws + 153600000);
  int*   cnt_item = (int*)(ws + 154400000);
  unsigned short* Wp_user = (unsigned short*)(ws + 154800000);
  unsigned short* Wp_item = (unsigned short*)(ws + 154865536);
  float* bias_user = (float*)(ws + 154931072);
  float* bias_item = (float*)(ws + 154931584);

  // zero agg + cnt (ws is poisoned 0xAA before every call)
  hipMemsetAsync(d_ws, 0, 154800000, stream);

  fuse_weights<<<dim3(128, 4), 128, 0, stream>>>(Wl_iu, Wr_iu, Wl_ui, Wr_ui,
                                                 W_user, W_item, Wp_user, Wp_item);
  fuse_bias<<<2, 128, 0, stream>>>(bl_iu, b_user, W_user, bl_ui, b_item, W_item,
                                   bias_user, bias_item);

  const int SC_BLOCKS = (EE * 64) / 256;   // 150000
  // user->item edges aggregate x_user into agg_item
  scatter<<<SC_BLOCKS, 256, 0, stream>>>(x_user, esrc_ui, edst_ui, agg_item, cnt_item);
  // item->user edges aggregate x_item into agg_user
  scatter<<<SC_BLOCKS, 256, 0, stream>>>(x_item, esrc_iu, edst_iu, agg_user, cnt_user);

  fused_gemm<<<(NUu + 63) / 64, 256, 0, stream>>>(x_user, agg_user, cnt_user,
                                                  Wp_user, bias_user, out, NUu);
  fused_gemm<<<(NIi + 63) / 64, 256, 0, stream>>>(x_item, agg_item, cnt_item,
                                                  Wp_item, bias_item,
                                                  out + (size_t)NUu * 128, NIi);
}

// Round 2
// 718.563 us; speedup vs baseline: 2.0454x; 2.0454x over previous
//
#include <hip/hip_runtime.h>

// Problem constants (from reference)
#define NUu 200000
#define NIi 100000
#define EE  600000
// D = H = 128

typedef short short8 __attribute__((ext_vector_type(8)));
typedef float floatx4 __attribute__((ext_vector_type(4)));

// float -> bf16 bits, round-to-nearest-even
__device__ __forceinline__ unsigned short f2bf(float f) {
  union { float f; unsigned int u; } v; v.f = f;
  unsigned int r = v.u + 0x7FFFu + ((v.u >> 16) & 1u);
  return (unsigned short)(r >> 16);
}

// ---------------------------------------------------------------------------
// K0a: fused weights  W1 = Wl @ W2nd,  W2 = Wr @ W2nd  -> bf16, packed in the
// MFMA B-fragment layout:  elem index = ((n_tile*8 + k_step)*64 + quad*16 + n_lo)*8 + j
// where k_global = k_step*32 + quad*8 + j, n = n_tile*16 + n_lo.
// ---------------------------------------------------------------------------
__global__ __launch_bounds__(128) void fuse_weights(
    const float* __restrict__ Wl_iu, const float* __restrict__ Wr_iu,
    const float* __restrict__ Wl_ui, const float* __restrict__ Wr_ui,
    const float* __restrict__ W_user, const float* __restrict__ W_item,
    unsigned short* __restrict__ Wp_user, unsigned short* __restrict__ Wp_item)
{
  int d = blockIdx.x;        // 0..127 (row of first factor)
  int m = blockIdx.y;        // which matrix
  int h = threadIdx.x;       // 0..127 (output col)
  const float* A; const float* W; unsigned short* dst; int koff;
  switch (m) {
    case 0:  A = Wl_iu; W = W_user; dst = Wp_user; koff = 0;   break;
    case 1:  A = Wr_iu; W = W_user; dst = Wp_user; koff = 128; break;
    case 2:  A = Wl_ui; W = W_item; dst = Wp_item; koff = 0;   break;
    default: A = Wr_ui; W = W_item; dst = Wp_item; koff = 128; break;
  }
  float acc = 0.f;
  for (int k = 0; k < 128; ++k) acc += A[d * 128 + k] * W[k * 128 + h];
  int kg = koff + d;
  int ks = kg >> 5, quad = (kg >> 3) & 3, j = kg & 7;
  int nt = h >> 4, nlo = h & 15;
  int idx = ((nt * 8 + ks) * 64 + quad * 16 + nlo) * 8 + j;
  dst[idx] = f2bf(acc);
}

// K0b: fused bias = bl @ W2nd + b2nd   (fp32). grid 2, block 128.
__global__ __launch_bounds__(128) void fuse_bias(
    const float* __restrict__ bl_iu, const float* __restrict__ b_user, const float* __restrict__ Wu,
    const float* __restrict__ bl_ui, const float* __restrict__ b_item, const float* __restrict__ Wi,
    float* __restrict__ bias_user, float* __restrict__ bias_item)
{
  int h = threadIdx.x;
  const float* bl = blockIdx.x ? bl_ui : bl_iu;
  const float* b2 = blockIdx.x ? b_item : b_user;
  const float* W  = blockIdx.x ? Wi : Wu;
  float* o        = blockIdx.x ? bias_item : bias_user;
  float acc = b2[h];
  for (int k = 0; k < 128; ++k) acc += bl[k] * W[k * 128 + h];
  o[h] = acc;
}

// ---------------------------------------------------------------------------
// CSR construction: hist -> scan1 (block sums) -> scan2 (scan of block sums)
// -> scan3 (per-element exclusive scan, writes row_ptr + fill cursors)
// -> fill (dst-sorted src list). Only int atomics on small L2-resident arrays.
// ---------------------------------------------------------------------------
__global__ __launch_bounds__(256) void hist(const int* __restrict__ edst,
                                            int* __restrict__ cnt, int E)
{
  int e = blockIdx.x * 256 + threadIdx.x;
  if (e < E) atomicAdd(&cnt[edst[e]], 1);
}

// block sums over 1024-element tiles
__global__ __launch_bounds__(256) void scan1(const int* __restrict__ cnt,
                                             int* __restrict__ blksum, int N)
{
  __shared__ int s[256];
  int b = blockIdx.x, t = threadIdx.x;
  int base = b * 1024 + t * 4;
  int v = 0;
  #pragma unroll
  for (int j = 0; j < 4; ++j) { int i = base + j; if (i < N) v += cnt[i]; }
  s[t] = v; __syncthreads();
  for (int off = 128; off > 0; off >>= 1) {
    if (t < off) s[t] += s[t + off];
    __syncthreads();
  }
  if (t == 0) blksum[b] = s[0];
}

// exclusive scan of <=256 block sums, single block
__global__ __launch_bounds__(256) void scan2(const int* __restrict__ blksum,
                                             int* __restrict__ blkoff, int nblk)
{
  __shared__ int s[256];
  int t = threadIdx.x;
  int v = t < nblk ? blksum[t] : 0;
  s[t] = v; __syncthreads();
  for (int off = 1; off < 256; off <<= 1) {
    int tmp = t >= off ? s[t - off] : 0;
    __syncthreads();
    s[t] += tmp;
    __syncthreads();
  }
  if (t < nblk) blkoff[t] = s[t] - v;
}

// per-element exclusive scan within each 1024-tile + block offset
__global__ __launch_bounds__(256) void scan3(const int* __restrict__ cnt,
                                             const int* __restrict__ blkoff,
                                             int* __restrict__ rowp,
                                             int* __restrict__ fillp, int N)
{
  __shared__ int s[256];
  int b = blockIdx.x, t = threadIdx.x;
  int base = b * 1024 + t * 4;
  int v[4]; int sum = 0;
  #pragma unroll
  for (int j = 0; j < 4; ++j) { int i = base + j; v[j] = (i < N) ? cnt[i] : 0; sum += v[j]; }
  s[t] = sum; __syncthreads();
  for (int off = 1; off < 256; off <<= 1) {
    int tmp = t >= off ? s[t - off] : 0;
    __syncthreads();
    s[t] += tmp;
    __syncthreads();
  }
  int ex = s[t] - sum + blkoff[b];
  #pragma unroll
  for (int j = 0; j < 4; ++j) {
    int i = base + j;
    if (i < N) { rowp[i] = ex; fillp[i] = ex; ex += v[j]; }
  }
}

__global__ __launch_bounds__(256) void fill(const int* __restrict__ esrc,
                                            const int* __restrict__ edst,
                                            int* __restrict__ fillp,
                                            int* __restrict__ srcs, int E)
{
  int e = blockIdx.x * 256 + threadIdx.x;
  if (e < E) {
    int d = edst[e];
    int p = atomicAdd(&fillp[d], 1);
    srcs[p] = esrc[e];
  }
}

// ---------------------------------------------------------------------------
// K3: fused node kernel with in-place mean aggregation:
//   out = relu( mean_{s in N(node)} x_src[s] @ W1 + x_own @ W2 + bias )
// One block = 64 nodes x 128 outputs. A (64x256, bf16) staged in LDS in the
// MFMA A-frag layout; first 128 k = gathered mean (CSR), last 128 k = own row.
// mfma_f32_16x16x32_bf16 C/D: col=lane&15, row=(lane>>4)*4+reg   (m89/m91)
// ---------------------------------------------------------------------------
__global__ __launch_bounds__(256, 2) void fused_gemm(
    const float* __restrict__ xown, const float* __restrict__ xsrc,
    const int* __restrict__ rowp, const int* __restrict__ cnt,
    const int* __restrict__ srcs, const unsigned short* __restrict__ Wp,
    const float* __restrict__ bias, float* __restrict__ outbase, int nvalid)
{
  __shared__ uint4 ldsA4[2048];                    // 32 KB packed A
  int t = threadIdx.x;
  int node0 = blockIdx.x * 64;

  // ---- stage A: 64 nodes x 256 k (k<128: gathered mean, k>=128: own x) ----
  #pragma unroll
  for (int i = 0; i < 8; ++i) {
    int oid = t + i * 256;                         // 0..2047 octet id
    int m = oid >> 5;                              // node within block (0..63)
    int oct = oid & 31;                            // 8-float chunk
    int node = node0 + m;
    float vals[8];
    if (node < nvalid) {
      if (oct < 16) {                              // aggregation half, k0=oct*8
        int k0 = oct * 8;
        int rs = rowp[node];
        int deg = cnt[node];
        float a0=0,a1=0,a2=0,a3=0,a4=0,a5=0,a6=0,a7=0;
        for (int e = 0; e < deg; ++e) {
          int sidx = srcs[rs + e];
          const float4* p = (const float4*)(xsrc + (size_t)sidx * 128 + k0);
          float4 lo = p[0], hi = p[1];
          a0 += lo.x; a1 += lo.y; a2 += lo.z; a3 += lo.w;
          a4 += hi.x; a5 += hi.y; a6 += hi.z; a7 += hi.w;
        }
        float sc = 1.0f / (float)(deg > 0 ? deg : 1);
        vals[0]=a0*sc; vals[1]=a1*sc; vals[2]=a2*sc; vals[3]=a3*sc;
        vals[4]=a4*sc; vals[5]=a5*sc; vals[6]=a6*sc; vals[7]=a7*sc;
      } else {                                     // own-feature half
        int k0 = (oct - 16) * 8;
        const float4* p = (const float4*)(xown + (size_t)node * 128 + k0);
        float4 lo = p[0], hi = p[1];
        vals[0]=lo.x; vals[1]=lo.y; vals[2]=lo.z; vals[3]=lo.w;
        vals[4]=hi.x; vals[5]=hi.y; vals[6]=hi.z; vals[7]=hi.w;
      }
    } else {
      #pragma unroll
      for (int j2 = 0; j2 < 8; ++j2) vals[j2] = 0.f;
    }
    uint4 p;
    p.x = (unsigned)f2bf(vals[0]) | ((unsigned)f2bf(vals[1]) << 16);
    p.y = (unsigned)f2bf(vals[2]) | ((unsigned)f2bf(vals[3]) << 16);
    p.z = (unsigned)f2bf(vals[4]) | ((unsigned)f2bf(vals[5]) << 16);
    p.w = (unsigned)f2bf(vals[6]) | ((unsigned)f2bf(vals[7]) << 16);
    int ks = oct >> 2, quad = oct & 3;             // k_global = oct*8 (0..255)
    int mt = m >> 4, mlo = m & 15;
    ldsA4[(mt * 8 + ks) * 64 + quad * 16 + mlo] = p;
  }
  __syncthreads();

  // ---- MFMA: wave = m-tile (16 nodes), 8 n-tiles, K = 256 in 8 steps ----
  int wave = t >> 6, lane = t & 63;
  floatx4 acc[8];
  #pragma unroll
  for (int i = 0; i < 8; ++i) acc[i] = (floatx4){0.f, 0.f, 0.f, 0.f};
  const short8* A = (const short8*)ldsA4;
  const short8* B = (const short8*)Wp;
  #pragma unroll
  for (int ks = 0; ks < 8; ++ks) {
    short8 af = A[(wave * 8 + ks) * 64 + lane];
    #pragma unroll
    for (int nt = 0; nt < 8; ++nt) {
      short8 bf = B[(nt * 8 + ks) * 64 + lane];
      acc[nt] = __builtin_amdgcn_mfma_f32_16x16x32_bf16(af, bf, acc[nt], 0, 0, 0);
    }
  }

  // ---- epilogue: bias + relu ----
  int col = lane & 15, qrow = (lane >> 4) * 4;
  #pragma unroll
  for (int nt = 0; nt < 8; ++nt) {
    int n = nt * 16 + col;
    float bv = bias[n];
    #pragma unroll
    for (int r = 0; r < 4; ++r) {
      int node = node0 + wave * 16 + qrow + r;
      if (node < nvalid) {
        float v = acc[nt][r] + bv;
        outbase[(size_t)node * 128 + n] = v > 0.f ? v : 0.f;
      }
    }
  }
}

// ---------------------------------------------------------------------------
// Workspace layout (bytes), total ~8.54 MB:
//   cnt_user   @ 0         800000      (zeroed each call)
//   cnt_item   @ 800000    400000      (zeroed each call)
//   row_user   @ 1200000   800000
//   row_item   @ 2000000   400000
//   fill_user  @ 2400000   800000
//   fill_item  @ 3200000   400000
//   srcs_user  @ 3600000   2400000     (item ids, dst-sorted, for agg_user)
//   srcs_item  @ 6000000   2400000     (user ids, dst-sorted, for agg_item)
//   blks_user  @ 8400000   1024
//   blks_item  @ 8401024   1024
//   boff_user  @ 8402048   1024
//   boff_item  @ 8403072   1024
//   Wp_user    @ 8404224   65536
//   Wp_item    @ 8469760   65536
//   bias_user  @ 8535296   512
//   bias_item  @ 8535808   512
// ---------------------------------------------------------------------------
extern "C" void kernel_launch(void* const* d_in, const int* in_sizes, int n_in,
                              void* d_out, int out_size, void* d_ws, size_t ws_size,
                              hipStream_t stream)
{
  const float* x_user = (const float*)d_in[0];
  const float* x_item = (const float*)d_in[1];
  const int* esrc_ui  = (const int*)d_in[2];
  const int* edst_ui  = (const int*)d_in[3];
  const int* esrc_iu  = (const int*)d_in[4];
  const int* edst_iu  = (const int*)d_in[5];
  const float* Wl_ui  = (const float*)d_in[6];
  const float* Wr_ui  = (const float*)d_in[8];
  const float* bl_ui  = (const float*)d_in[7];
  const float* Wl_iu  = (const float*)d_in[9];
  const float* bl_iu  = (const float*)d_in[10];
  const float* Wr_iu  = (const float*)d_in[11];
  const float* W_user = (const float*)d_in[12];
  const float* b_user = (const float*)d_in[13];
  const float* W_item = (const float*)d_in[14];
  const float* b_item = (const float*)d_in[15];
  float* out = (float*)d_out;

  char* ws = (char*)d_ws;
  int* cnt_user  = (int*)(ws + 0);
  int* cnt_item  = (int*)(ws + 800000);
  int* row_user  = (int*)(ws + 1200000);
  int* row_item  = (int*)(ws + 2000000);
  int* fill_user = (int*)(ws + 2400000);
  int* fill_item = (int*)(ws + 3200000);
  int* srcs_user = (int*)(ws + 3600000);
  int* srcs_item = (int*)(ws + 6000000);
  int* blks_user = (int*)(ws + 8400000);
  int* blks_item = (int*)(ws + 8401024);
  int* boff_user = (int*)(ws + 8402048);
  int* boff_item = (int*)(ws + 8403072);
  unsigned short* Wp_user = (unsigned short*)(ws + 8404224);
  unsigned short* Wp_item = (unsigned short*)(ws + 8469760);
  float* bias_user = (float*)(ws + 8535296);
  float* bias_item = (float*)(ws + 8535808);

  // zero only the histograms (1.2 MB)
  hipMemsetAsync(d_ws, 0, 1200000, stream);

  fuse_weights<<<dim3(128, 4), 128, 0, stream>>>(Wl_iu, Wr_iu, Wl_ui, Wr_ui,
                                                 W_user, W_item, Wp_user, Wp_item);
  fuse_bias<<<2, 128, 0, stream>>>(bl_iu, b_user, W_user, bl_ui, b_item, W_item,
                                   bias_user, bias_item);

  const int EB = (EE + 255) / 256;            // 2344
  const int NBU = (NUu + 1023) / 1024;        // 196
  const int NBI = (NIi + 1023) / 1024;        // 98

  // CSR for user rows (iu edges: src=item, dst=user)
  hist<<<EB, 256, 0, stream>>>(edst_iu, cnt_user, EE);
  // CSR for item rows (ui edges: src=user, dst=item)
  hist<<<EB, 256, 0, stream>>>(edst_ui, cnt_item, EE);

  scan1<<<NBU, 256, 0, stream>>>(cnt_user, blks_user, NUu);
  scan1<<<NBI, 256, 0, stream>>>(cnt_item, blks_item, NIi);
  scan2<<<1, 256, 0, stream>>>(blks_user, boff_user, NBU);
  scan2<<<1, 256, 0, stream>>>(blks_item, boff_item, NBI);
  scan3<<<NBU, 256, 0, stream>>>(cnt_user, boff_user, row_user, fill_user, NUu);
  scan3<<<NBI, 256, 0, stream>>>(cnt_item, boff_item, row_item, fill_item, NIi);

  fill<<<EB, 256, 0, stream>>>(esrc_iu, edst_iu, fill_user, srcs_user, EE);
  fill<<<EB, 256, 0, stream>>>(esrc_ui, edst_ui, fill_item, srcs_item, EE);

  // fused mean-aggregate + double-GEMM + bias + relu
  fused_gemm<<<(NUu + 63) / 64, 256, 0, stream>>>(x_user, x_item, row_user, cnt_user,
                                                  srcs_user, Wp_user, bias_user,
                                                  out, NUu);
  fused_gemm<<<(NIi + 63) / 64, 256, 0, stream>>>(x_item, x_user, row_item, cnt_item,
                                                  srcs_item, Wp_item, bias_item,
                                                  out + (size_t)NUu * 128, NIi);
}